// Round 3
// baseline (4634.426 us; speedup 1.0000x reference)
//
#include <hip/hip_runtime.h>
#include <hip/hip_fp16.h>
#include <stdint.h>

#define N_NODES 400000
#define N_EDGES 1600000
#define N_GRAPHS 10000
#define SLOPE 0.01f

typedef _Float16 hf4 __attribute__((ext_vector_type(4)));

__device__ __forceinline__ float lrelu(float x) { return x > 0.f ? x : SLOPE * x; }

// ---------------------------------------------------------------------------
// Fold: WeWi[13][64] = We @ Wi_bot ; bfold[64] = bi + be @ Wi_bot
__global__ void k_fold(const float* We, const float* be, const float* Wi, const float* bi,
                       float* WeWi, float* bfold) {
    int j = threadIdx.x;  // 64 threads
    for (int d = 0; d < 13; d++) {
        float acc = 0.f;
        for (int k = 0; k < 64; k++) acc += We[d * 64 + k] * Wi[(64 + k) * 64 + j];
        WeWi[d * 64 + j] = acc;
    }
    float accb = bi[j];
    for (int k = 0; k < 64; k++) accb += be[k] * Wi[(64 + k) * 64 + j];
    bfold[j] = accb;
}

// ---------------------------------------------------------------------------
// nodeWi = (nf @ Wn + bn) @ Wi_top   (fp16 out; node recomputed later in k_nodeout)
__global__ __launch_bounds__(256) void k_node(const float* nf, const float* Wn,
                                              const float* bn, const float* Wi,
                                              _Float16* nodeWi) {
    __shared__ float nodeL[4096];
    __shared__ float buf[9472];  // phase1: feats[4736] | WnL[4736]; phase2: WiT[4096]
    int t = threadIdx.x;
    int n0 = blockIdx.x * 64;
    float* feats = buf;
    float* WnL = buf + 4736;
    for (int v = t; v < 4736; v += 256) feats[v] = nf[(size_t)n0 * 74 + v];
    for (int v = t; v < 4736; v += 256) WnL[v] = Wn[v];
    __syncthreads();
    int j = t & 63, sub = t >> 6;
    float bnj = bn[j];
    for (int i = 0; i < 16; i++) {
        int r = sub + 4 * i;
        float acc = bnj;
        const float* fr = &feats[r * 74];
        for (int k = 0; k < 74; k++) acc += fr[k] * WnL[k * 64 + j];
        nodeL[r * 64 + j] = acc;
    }
    __syncthreads();  // everyone done with feats/WnL
    float* WiT = buf;
    for (int v = t; v < 4096; v += 256) WiT[v] = Wi[v];  // rows 0..63 of Wi
    __syncthreads();
    for (int i = 0; i < 16; i++) {
        int r = sub + 4 * i;
        float acc = 0.f;
        const float* xr = &nodeL[r * 64];
        for (int k = 0; k < 64; k++) acc += xr[k] * WiT[k * 64 + j];
        nodeWi[(size_t)(n0 + r) * 64 + j] = (_Float16)acc;
    }
}

// ---------------------------------------------------------------------------
// h = lrelu(nodeWi[src] + ef @ WeWi + bfold)   (fp16; h0 NOT stored)
__global__ __launch_bounds__(256) void k_h0(const float* ef, const int* src,
                                            const float* WeWi, const float* bfold,
                                            const _Float16* nodeWi, _Float16* h) {
    __shared__ float efL[832];
    __shared__ float WW[832];
    __shared__ float bf[64];
    int t = threadIdx.x;
    int e0 = blockIdx.x * 64;
    for (int v = t; v < 832; v += 256) efL[v] = ef[(size_t)e0 * 13 + v];
    for (int v = t; v < 832; v += 256) WW[v] = WeWi[v];
    if (t < 64) bf[t] = bfold[t];
    __syncthreads();
    int j = t & 63, sub = t >> 6;
    for (int i = 0; i < 16; i++) {
        int el = sub + 4 * i;
        int e = e0 + el;
        float acc = bf[j];
        for (int d = 0; d < 13; d++) acc += efL[el * 13 + d] * WW[d * 64 + j];
        acc += (float)nodeWi[(size_t)src[e] * 64 + j];
        h[(size_t)e * 64 + j] = (_Float16)lrelu(acc);
    }
}

// ---------------------------------------------------------------------------
// agg[dst[e]] += h[e]   (packed-fp16 atomics; agg pre-zeroed)
__global__ __launch_bounds__(256) void k_scatter(const __half2* h2, const int* dst,
                                                 __half2* agg2) {
    int gid = blockIdx.x * 256 + threadIdx.x;  // < E*32
    int e = gid >> 5, j2 = gid & 31;
    int d = dst[e];
    unsafeAtomicAdd(&agg2[d * 32 + j2], h2[gid]);
}

// ---------------------------------------------------------------------------
// h = lrelu(h0 + (agg[src] - h[rev]) @ Wl[l] + bl[l])  IN-PLACE on h, with
// h0 = lrelu(nodeWi[src] + ef@WeWi + bfold) recomputed in the epilogue.
// Safe in-place: e and e^1 share the 64-aligned tile; h reads before barrier,
// writes after; no cross-block h access (agg/nodeWi are separate arrays).
__global__ __launch_bounds__(256) void k_conv(const _Float16* agg, _Float16* h,
                                              const _Float16* nodeWi, const float* ef,
                                              const int* src, const float* WeWi,
                                              const float* bfold, const float* Wl_g,
                                              const float* bl_g, int layer) {
    __shared__ float4 WL[64][17];  // [k][j4], padded
    __shared__ float4 ML[64][17];  // [e][k4], padded
    __shared__ float efL[832];
    __shared__ float WWL[832];
    __shared__ float bfL[64];
    __shared__ int srcL[64];
    int t = threadIdx.x;
    int e0 = blockIdx.x * 64;
    const float* Wlp = Wl_g + layer * 4096;
    for (int i = 0; i < 4; i++) {
        int idx = t + 256 * i;  // 0..1023
        int k = idx >> 4, j4 = idx & 15;
        WL[k][j4] = *(const float4*)(Wlp + k * 64 + j4 * 4);
    }
    for (int v = t; v < 832; v += 256) efL[v] = ef[(size_t)e0 * 13 + v];
    for (int v = t; v < 832; v += 256) WWL[v] = WeWi[v];
    if (t < 64) { bfL[t] = bfold[t]; srcL[t] = src[e0 + t]; }
    for (int i = 0; i < 4; i++) {
        int idx = t + 256 * i;
        int e = idx >> 4, k4 = idx & 15;
        int ge = e0 + e;
        int s = src[ge];
        hf4 av = *(const hf4*)(agg + (size_t)s * 64 + k4 * 4);
        hf4 hv = *(const hf4*)(h + (size_t)(ge ^ 1) * 64 + k4 * 4);
        ML[e][k4] = make_float4((float)av.x - (float)hv.x, (float)av.y - (float)hv.y,
                                (float)av.z - (float)hv.z, (float)av.w - (float)hv.w);
    }
    __syncthreads();
    int jg = t & 7, eg = t >> 3;  // eg in 0..31
    int j0 = jg * 8;
    float4 a00 = {0, 0, 0, 0}, a01 = {0, 0, 0, 0}, a10 = {0, 0, 0, 0}, a11 = {0, 0, 0, 0};
    for (int kk = 0; kk < 16; kk++) {
        float4 m0 = ML[eg][kk];
        float4 m1 = ML[eg + 32][kk];
#pragma unroll
        for (int c = 0; c < 4; c++) {
            int k = kk * 4 + c;
            float4 w0 = WL[k][jg * 2];
            float4 w1 = WL[k][jg * 2 + 1];
            float mk0 = (c == 0) ? m0.x : (c == 1) ? m0.y : (c == 2) ? m0.z : m0.w;
            float mk1 = (c == 0) ? m1.x : (c == 1) ? m1.y : (c == 2) ? m1.z : m1.w;
            a00.x += mk0 * w0.x; a00.y += mk0 * w0.y; a00.z += mk0 * w0.z; a00.w += mk0 * w0.w;
            a01.x += mk0 * w1.x; a01.y += mk0 * w1.y; a01.z += mk0 * w1.z; a01.w += mk0 * w1.w;
            a10.x += mk1 * w0.x; a10.y += mk1 * w0.y; a10.z += mk1 * w0.z; a10.w += mk1 * w0.w;
            a11.x += mk1 * w1.x; a11.y += mk1 * w1.y; a11.z += mk1 * w1.z; a11.w += mk1 * w1.w;
        }
    }
    float4 bl0 = *(const float4*)(bl_g + layer * 64 + j0);
    float4 bl1 = *(const float4*)(bl_g + layer * 64 + j0 + 4);
    float4 bf0 = *(const float4*)&bfL[j0];
    float4 bf1 = *(const float4*)&bfL[j0 + 4];
#pragma unroll
    for (int half = 0; half < 2; half++) {
        int el = eg + half * 32;
        int ge = e0 + el;
        int s = srcL[el];
        hf4 nw0 = *(const hf4*)(nodeWi + (size_t)s * 64 + j0);
        hf4 nw1 = *(const hf4*)(nodeWi + (size_t)s * 64 + j0 + 4);
        float4 z0 = make_float4(bf0.x + (float)nw0.x, bf0.y + (float)nw0.y,
                                bf0.z + (float)nw0.z, bf0.w + (float)nw0.w);
        float4 z1 = make_float4(bf1.x + (float)nw1.x, bf1.y + (float)nw1.y,
                                bf1.z + (float)nw1.z, bf1.w + (float)nw1.w);
        const float* er = &efL[el * 13];
#pragma unroll
        for (int d = 0; d < 13; d++) {
            float ed = er[d];
            float4 w0 = *(const float4*)&WWL[d * 64 + j0];
            float4 w1 = *(const float4*)&WWL[d * 64 + j0 + 4];
            z0.x += ed * w0.x; z0.y += ed * w0.y; z0.z += ed * w0.z; z0.w += ed * w0.w;
            z1.x += ed * w1.x; z1.y += ed * w1.y; z1.z += ed * w1.z; z1.w += ed * w1.w;
        }
        float4 aa0 = half ? a10 : a00;
        float4 aa1 = half ? a11 : a01;
        hf4 olo, ohi;
        olo.x = (_Float16)lrelu(lrelu(z0.x) + aa0.x + bl0.x);
        olo.y = (_Float16)lrelu(lrelu(z0.y) + aa0.y + bl0.y);
        olo.z = (_Float16)lrelu(lrelu(z0.z) + aa0.z + bl0.z);
        olo.w = (_Float16)lrelu(lrelu(z0.w) + aa0.w + bl0.w);
        ohi.x = (_Float16)lrelu(lrelu(z1.x) + aa1.x + bl1.x);
        ohi.y = (_Float16)lrelu(lrelu(z1.y) + aa1.y + bl1.y);
        ohi.z = (_Float16)lrelu(lrelu(z1.z) + aa1.z + bl1.z);
        ohi.w = (_Float16)lrelu(lrelu(z1.w) + aa1.w + bl1.w);
        *(hf4*)(h + (size_t)ge * 64 + j0) = olo;
        *(hf4*)(h + (size_t)ge * 64 + j0 + 4) = ohi;
    }
}

// ---------------------------------------------------------------------------
// node recomputed from nf; node_h = lrelu([node, agg] @ Wa + ba); g[gid] += node_h
__global__ __launch_bounds__(256) void k_nodeout(const float* nf, const float* Wn,
                                                 const float* bn, const _Float16* agg,
                                                 const float* Wa, const float* ba,
                                                 const int* gidp, float* g) {
    __shared__ float nodeL[4096];
    __shared__ float buf[10240];  // p1: feats[4736]|WnL[4736]; p2: WaL[8192]|aggL16[4096h]
    int t = threadIdx.x;
    int n0 = blockIdx.x * 64;
    float* feats = buf;
    float* WnL = buf + 4736;
    for (int v = t; v < 4736; v += 256) feats[v] = nf[(size_t)n0 * 74 + v];
    for (int v = t; v < 4736; v += 256) WnL[v] = Wn[v];
    __syncthreads();
    int j = t & 63, sub = t >> 6;
    float bnj = bn[j];
    for (int i = 0; i < 16; i++) {
        int r = sub + 4 * i;
        float acc = bnj;
        const float* fr = &feats[r * 74];
        for (int k = 0; k < 74; k++) acc += fr[k] * WnL[k * 64 + j];
        nodeL[r * 64 + j] = acc;
    }
    __syncthreads();
    float* WaL = buf;                          // 8192 floats
    _Float16* aggL = (_Float16*)(buf + 8192);  // 4096 halfs
    for (int v = t; v < 8192; v += 256) WaL[v] = Wa[v];
    for (int v = t; v < 4096; v += 256) aggL[v] = agg[(size_t)n0 * 64 + v];
    __syncthreads();
    float baj = ba[j];
    for (int i = 0; i < 16; i++) {
        int r = sub + 4 * i;
        float acc = baj;
        const float* xr = &nodeL[r * 64];
        const _Float16* ar = &aggL[r * 64];
        for (int k = 0; k < 64; k++)
            acc += xr[k] * WaL[k * 64 + j] + (float)ar[k] * WaL[(64 + k) * 64 + j];
        atomicAdd(&g[(size_t)gidp[n0 + r] * 64 + j], lrelu(acc));
    }
}

// ---------------------------------------------------------------------------
// out = lrelu(g @ W1 + b1) @ W2 + b2   (one wave per graph)
__global__ __launch_bounds__(256) void k_head(const float* g, const float* W1,
                                              const float* b1, const float* W2,
                                              const float* b2, float* out) {
    __shared__ float W1L[4096];
    int t = threadIdx.x;
    for (int v = t; v < 4096; v += 256) W1L[v] = W1[v];
    __syncthreads();
    int w = t >> 6, j = t & 63;
    int graph = blockIdx.x * 4 + w;
    if (graph >= N_GRAPHS) return;
    const float* gr = g + (size_t)graph * 64;
    float acc = b1[j];
    for (int k = 0; k < 64; k++) acc += gr[k] * W1L[k * 64 + j];
    float p = lrelu(acc) * W2[j];
    for (int off = 32; off > 0; off >>= 1) p += __shfl_down(p, off, 64);
    if (j == 0) out[graph] = p + b2[0];
}

// ---------------------------------------------------------------------------
extern "C" void kernel_launch(void* const* d_in, const int* in_sizes, int n_in,
                              void* d_out, int out_size, void* d_ws, size_t ws_size,
                              hipStream_t stream) {
    const float* nf = (const float*)d_in[0];
    const float* ef = (const float*)d_in[1];
    const int* src = (const int*)d_in[2];
    const int* dst = (const int*)d_in[3];
    const int* gid = (const int*)d_in[4];
    const float* Wn = (const float*)d_in[5];
    const float* bn = (const float*)d_in[6];
    const float* We = (const float*)d_in[7];
    const float* be = (const float*)d_in[8];
    const float* Wi = (const float*)d_in[9];
    const float* bi = (const float*)d_in[10];
    const float* Wa = (const float*)d_in[11];
    const float* ba = (const float*)d_in[12];
    const float* Wl = (const float*)d_in[13];
    const float* bl = (const float*)d_in[14];
    const float* W1 = (const float*)d_in[15];
    const float* b1 = (const float*)d_in[16];
    const float* W2 = (const float*)d_in[17];
    const float* b2 = (const float*)d_in[18];

    char* ws = (char*)d_ws;
    size_t off = 0;
    auto alloc = [&](size_t bytes) -> char* {
        char* p = ws + off;
        off += (bytes + 255) & ~(size_t)255;
        return p;
    };
    // total ~295.5 MiB
    float* WeWi = (float*)alloc(13 * 64 * 4);
    float* bfold = (float*)alloc(64 * 4);
    _Float16* nodeWi = (_Float16*)alloc((size_t)N_NODES * 64 * 2);
    _Float16* h = (_Float16*)alloc((size_t)N_EDGES * 64 * 2);
    _Float16* agg = (_Float16*)alloc((size_t)N_NODES * 64 * 2);
    float* g = (float*)alloc((size_t)N_GRAPHS * 64 * 4);

    hipLaunchKernelGGL(k_fold, dim3(1), dim3(64), 0, stream, We, be, Wi, bi, WeWi, bfold);
    hipLaunchKernelGGL(k_node, dim3(N_NODES / 64), dim3(256), 0, stream, nf, Wn, bn, Wi, nodeWi);
    hipLaunchKernelGGL(k_h0, dim3(N_EDGES / 64), dim3(256), 0, stream, ef, src, WeWi, bfold,
                       nodeWi, h);

    for (int l = 0; l < 4; l++) {
        hipMemsetAsync(agg, 0, (size_t)N_NODES * 64 * 2, stream);
        hipLaunchKernelGGL(k_scatter, dim3(N_EDGES * 32 / 256), dim3(256), 0, stream,
                           (const __half2*)h, dst, (__half2*)agg);
        hipLaunchKernelGGL(k_conv, dim3(N_EDGES / 64), dim3(256), 0, stream, agg, h, nodeWi,
                           ef, src, WeWi, bfold, Wl, bl, l);
    }
    hipMemsetAsync(agg, 0, (size_t)N_NODES * 64 * 2, stream);
    hipLaunchKernelGGL(k_scatter, dim3(N_EDGES * 32 / 256), dim3(256), 0, stream,
                       (const __half2*)h, dst, (__half2*)agg);
    hipMemsetAsync(g, 0, (size_t)N_GRAPHS * 64 * 4, stream);
    hipLaunchKernelGGL(k_nodeout, dim3(N_NODES / 64), dim3(256), 0, stream, nf, Wn, bn, agg,
                       Wa, ba, gid, g);
    hipLaunchKernelGGL(k_head, dim3(N_GRAPHS / 4), dim3(256), 0, stream, g, W1, b1, W2, b2,
                       (float*)d_out);
}

// Round 4
// 3761.126 us; speedup vs baseline: 1.2322x; 1.2322x over previous
//
#include <hip/hip_runtime.h>
#include <hip/hip_fp16.h>
#include <stdint.h>

#define N_NODES 400000
#define N_EDGES 1600000
#define N_GRAPHS 10000
#define SLOPE 0.01f

typedef _Float16 hf4 __attribute__((ext_vector_type(4)));
typedef _Float16 hf8 __attribute__((ext_vector_type(8)));
typedef float f32x4 __attribute__((ext_vector_type(4)));

__device__ __forceinline__ float lrelu(float x) { return x > 0.f ? x : SLOPE * x; }

// ---------------------------------------------------------------------------
// Fold: WeWi[13][64] = We @ Wi_bot ; bfold[64] = bi + be @ Wi_bot
// Also: WlT16[l][j][k] = (fp16) Wl[l][k][j]   (transposed fp16 conv weights)
__global__ void k_fold(const float* We, const float* be, const float* Wi, const float* bi,
                       const float* Wl, float* WeWi, float* bfold, _Float16* WlT16) {
    int j = threadIdx.x;  // 64 threads
    for (int d = 0; d < 13; d++) {
        float acc = 0.f;
        for (int k = 0; k < 64; k++) acc += We[d * 64 + k] * Wi[(64 + k) * 64 + j];
        WeWi[d * 64 + j] = acc;
    }
    float accb = bi[j];
    for (int k = 0; k < 64; k++) accb += be[k] * Wi[(64 + k) * 64 + j];
    bfold[j] = accb;
    for (int l = 0; l < 4; l++)
        for (int k = 0; k < 64; k++)
            WlT16[l * 4096 + j * 64 + k] = (_Float16)Wl[l * 4096 + k * 64 + j];
}

// ---------------------------------------------------------------------------
// nodeWi = (nf @ Wn + bn) @ Wi_top   (fp16 out; node recomputed later in k_nodeout)
__global__ __launch_bounds__(256) void k_node(const float* nf, const float* Wn,
                                              const float* bn, const float* Wi,
                                              _Float16* nodeWi) {
    __shared__ float nodeL[4096];
    __shared__ float buf[9472];  // phase1: feats[4736] | WnL[4736]; phase2: WiT[4096]
    int t = threadIdx.x;
    int n0 = blockIdx.x * 64;
    float* feats = buf;
    float* WnL = buf + 4736;
    for (int v = t; v < 4736; v += 256) feats[v] = nf[(size_t)n0 * 74 + v];
    for (int v = t; v < 4736; v += 256) WnL[v] = Wn[v];
    __syncthreads();
    int j = t & 63, sub = t >> 6;
    float bnj = bn[j];
    for (int i = 0; i < 16; i++) {
        int r = sub + 4 * i;
        float acc = bnj;
        const float* fr = &feats[r * 74];
        for (int k = 0; k < 74; k++) acc += fr[k] * WnL[k * 64 + j];
        nodeL[r * 64 + j] = acc;
    }
    __syncthreads();  // everyone done with feats/WnL
    float* WiT = buf;
    for (int v = t; v < 4096; v += 256) WiT[v] = Wi[v];  // rows 0..63 of Wi
    __syncthreads();
    for (int i = 0; i < 16; i++) {
        int r = sub + 4 * i;
        float acc = 0.f;
        const float* xr = &nodeL[r * 64];
        for (int k = 0; k < 64; k++) acc += xr[k] * WiT[k * 64 + j];
        nodeWi[(size_t)(n0 + r) * 64 + j] = (_Float16)acc;
    }
}

// ---------------------------------------------------------------------------
// h = lrelu(nodeWi[src] + ef @ WeWi + bfold)   (fp16; h0 NOT stored)
__global__ __launch_bounds__(256) void k_h0(const float* ef, const int* src,
                                            const float* WeWi, const float* bfold,
                                            const _Float16* nodeWi, _Float16* h) {
    __shared__ float efL[832];
    __shared__ float WW[832];
    __shared__ float bf[64];
    int t = threadIdx.x;
    int e0 = blockIdx.x * 64;
    for (int v = t; v < 832; v += 256) efL[v] = ef[(size_t)e0 * 13 + v];
    for (int v = t; v < 832; v += 256) WW[v] = WeWi[v];
    if (t < 64) bf[t] = bfold[t];
    __syncthreads();
    int j = t & 63, sub = t >> 6;
    for (int i = 0; i < 16; i++) {
        int el = sub + 4 * i;
        int e = e0 + el;
        float acc = bf[j];
        for (int d = 0; d < 13; d++) acc += efL[el * 13 + d] * WW[d * 64 + j];
        acc += (float)nodeWi[(size_t)src[e] * 64 + j];
        h[(size_t)e * 64 + j] = (_Float16)lrelu(acc);
    }
}

// ---------------------------------------------------------------------------
// agg[dst[e]] += h[e]   (packed-fp16 atomics; agg pre-zeroed)
__global__ __launch_bounds__(256) void k_scatter(const __half2* h2, const int* dst,
                                                 __half2* agg2) {
    int gid = blockIdx.x * 256 + threadIdx.x;  // < E*32
    int e = gid >> 5, j2 = gid & 31;
    int d = dst[e];
    unsafeAtomicAdd(&agg2[d * 32 + j2], h2[gid]);
}

// ---------------------------------------------------------------------------
// h = lrelu(h0 + (agg[src] - h[rev]) @ Wl[l] + bl[l])  IN-PLACE on h.
// GEMM via MFMA f32_16x16x32_f16: M[64x64] (fp16, LDS) @ W[64x64] (fp16,
// transposed in LDS). C round-trips through LDS (union with M/WT region) so
// the epilogue (h0-recompute + bias + lrelu) keeps the coalesced
// column-per-thread pattern. h0 = lrelu(nodeWi[src] + ef@WeWi + bfold).
// In-place safe: e and e^1 share the 64-aligned tile; h reads before first
// barrier, writes after last; no cross-block h access.
__global__ __launch_bounds__(256) void k_conv(const _Float16* agg, _Float16* h,
                                              const _Float16* nodeWi, const float* ef,
                                              const int* src, const float* WeWi,
                                              const float* bfold, const _Float16* WlT16,
                                              const float* bl_g, int layer) {
    __shared__ __align__(16) char uni[18432];
    _Float16* Msh = (_Float16*)uni;           // [64][72] fp16 (phase A/B)
    _Float16* WTs = (_Float16*)(uni + 9216);  // [64][72] fp16 (phase A/B)
    float* Cs = (float*)uni;                  // [64][65] fp32 (phase C/D)
    __shared__ float efL[832];
    __shared__ float WWL[832];
    __shared__ float bfL[64];
    __shared__ int srcL[64];
    int t = threadIdx.x;
    int e0 = blockIdx.x * 64;
    const _Float16* WTg = WlT16 + layer * 4096;
    // --- phase A: stage WT, M, epilogue tables ---
    for (int i = 0; i < 4; i++) {
        int idx = t + 256 * i;  // 0..1023
        int r = idx >> 4, c4 = idx & 15;
        *(hf4*)&WTs[r * 72 + c4 * 4] = *(const hf4*)(WTg + r * 64 + c4 * 4);
    }
    for (int i = 0; i < 4; i++) {
        int idx = t + 256 * i;
        int e = idx >> 4, k4 = idx & 15;
        int ge = e0 + e;
        int s = src[ge];
        hf4 av = *(const hf4*)(agg + (size_t)s * 64 + k4 * 4);
        hf4 hv = *(const hf4*)(h + (size_t)(ge ^ 1) * 64 + k4 * 4);
        hf4 m;
        m.x = av.x - hv.x; m.y = av.y - hv.y; m.z = av.z - hv.z; m.w = av.w - hv.w;
        *(hf4*)&Msh[e * 72 + k4 * 4] = m;
    }
    for (int v = t; v < 832; v += 256) efL[v] = ef[(size_t)e0 * 13 + v];
    for (int v = t; v < 832; v += 256) WWL[v] = WeWi[v];
    if (t < 64) { bfL[t] = bfold[t]; srcL[t] = src[e0 + t]; }
    __syncthreads();
    // --- phase B: MFMA.  wave w handles edges [16w,16w+16) x all 64 cols ---
    int lane = t & 63, w = t >> 6;
    int m16 = lane & 15, quad = lane >> 4;
    f32x4 acc[4];
#pragma unroll
    for (int jt = 0; jt < 4; jt++) acc[jt] = (f32x4){0.f, 0.f, 0.f, 0.f};
#pragma unroll
    for (int kt = 0; kt < 2; kt++) {
        hf8 a = *(const hf8*)&Msh[(w * 16 + m16) * 72 + kt * 32 + quad * 8];
#pragma unroll
        for (int jt = 0; jt < 4; jt++) {
            hf8 b = *(const hf8*)&WTs[(jt * 16 + m16) * 72 + kt * 32 + quad * 8];
            acc[jt] = __builtin_amdgcn_mfma_f32_16x16x32_f16(a, b, acc[jt], 0, 0, 0);
        }
    }
    __syncthreads();  // all LDS reads of Msh/WTs done before overwrite
    // --- phase C: C -> LDS (C layout: col=lane&15, row=quad*4+reg) ---
#pragma unroll
    for (int jt = 0; jt < 4; jt++)
#pragma unroll
        for (int r = 0; r < 4; r++)
            Cs[(w * 16 + quad * 4 + r) * 65 + jt * 16 + m16] = acc[jt][r];
    __syncthreads();
    // --- phase D: epilogue, coalesced column-per-thread ---
    int j = t & 63, sub = t >> 6;
    float blj = bl_g[layer * 64 + j];
    float bfj = bfL[j];
    for (int i = 0; i < 16; i++) {
        int el = sub + 4 * i;
        int ge = e0 + el;
        int s = srcL[el];
        float z = bfj + (float)nodeWi[(size_t)s * 64 + j];
        const float* er = &efL[el * 13];
#pragma unroll
        for (int d = 0; d < 13; d++) z += er[d] * WWL[d * 64 + j];
        float val = lrelu(z) + Cs[el * 65 + j] + blj;
        h[(size_t)ge * 64 + j] = (_Float16)lrelu(val);
    }
}

// ---------------------------------------------------------------------------
// node recomputed from nf; node_h = lrelu([node, agg] @ Wa + ba); g[gid] += node_h
__global__ __launch_bounds__(256) void k_nodeout(const float* nf, const float* Wn,
                                                 const float* bn, const _Float16* agg,
                                                 const float* Wa, const float* ba,
                                                 const int* gidp, float* g) {
    __shared__ float nodeL[4096];
    __shared__ float buf[10240];  // p1: feats[4736]|WnL[4736]; p2: WaL[8192]|aggL16[4096h]
    int t = threadIdx.x;
    int n0 = blockIdx.x * 64;
    float* feats = buf;
    float* WnL = buf + 4736;
    for (int v = t; v < 4736; v += 256) feats[v] = nf[(size_t)n0 * 74 + v];
    for (int v = t; v < 4736; v += 256) WnL[v] = Wn[v];
    __syncthreads();
    int j = t & 63, sub = t >> 6;
    float bnj = bn[j];
    for (int i = 0; i < 16; i++) {
        int r = sub + 4 * i;
        float acc = bnj;
        const float* fr = &feats[r * 74];
        for (int k = 0; k < 74; k++) acc += fr[k] * WnL[k * 64 + j];
        nodeL[r * 64 + j] = acc;
    }
    __syncthreads();
    float* WaL = buf;                          // 8192 floats
    _Float16* aggL = (_Float16*)(buf + 8192);  // 4096 halfs
    for (int v = t; v < 8192; v += 256) WaL[v] = Wa[v];
    for (int v = t; v < 4096; v += 256) aggL[v] = agg[(size_t)n0 * 64 + v];
    __syncthreads();
    float baj = ba[j];
    for (int i = 0; i < 16; i++) {
        int r = sub + 4 * i;
        float acc = baj;
        const float* xr = &nodeL[r * 64];
        const _Float16* ar = &aggL[r * 64];
        for (int k = 0; k < 64; k++)
            acc += xr[k] * WaL[k * 64 + j] + (float)ar[k] * WaL[(64 + k) * 64 + j];
        atomicAdd(&g[(size_t)gidp[n0 + r] * 64 + j], lrelu(acc));
    }
}

// ---------------------------------------------------------------------------
// out = lrelu(g @ W1 + b1) @ W2 + b2   (one wave per graph)
__global__ __launch_bounds__(256) void k_head(const float* g, const float* W1,
                                              const float* b1, const float* W2,
                                              const float* b2, float* out) {
    __shared__ float W1L[4096];
    int t = threadIdx.x;
    for (int v = t; v < 4096; v += 256) W1L[v] = W1[v];
    __syncthreads();
    int w = t >> 6, j = t & 63;
    int graph = blockIdx.x * 4 + w;
    if (graph >= N_GRAPHS) return;
    const float* gr = g + (size_t)graph * 64;
    float acc = b1[j];
    for (int k = 0; k < 64; k++) acc += gr[k] * W1L[k * 64 + j];
    float p = lrelu(acc) * W2[j];
    for (int off = 32; off > 0; off >>= 1) p += __shfl_down(p, off, 64);
    if (j == 0) out[graph] = p + b2[0];
}

// ---------------------------------------------------------------------------
extern "C" void kernel_launch(void* const* d_in, const int* in_sizes, int n_in,
                              void* d_out, int out_size, void* d_ws, size_t ws_size,
                              hipStream_t stream) {
    const float* nf = (const float*)d_in[0];
    const float* ef = (const float*)d_in[1];
    const int* src = (const int*)d_in[2];
    const int* dst = (const int*)d_in[3];
    const int* gid = (const int*)d_in[4];
    const float* Wn = (const float*)d_in[5];
    const float* bn = (const float*)d_in[6];
    const float* We = (const float*)d_in[7];
    const float* be = (const float*)d_in[8];
    const float* Wi = (const float*)d_in[9];
    const float* bi = (const float*)d_in[10];
    const float* Wa = (const float*)d_in[11];
    const float* ba = (const float*)d_in[12];
    const float* Wl = (const float*)d_in[13];
    const float* bl = (const float*)d_in[14];
    const float* W1 = (const float*)d_in[15];
    const float* b1 = (const float*)d_in[16];
    const float* W2 = (const float*)d_in[17];
    const float* b2 = (const float*)d_in[18];

    char* ws = (char*)d_ws;
    size_t off = 0;
    auto alloc = [&](size_t bytes) -> char* {
        char* p = ws + off;
        off += (bytes + 255) & ~(size_t)255;
        return p;
    };
    // total ~295.6 MiB
    float* WeWi = (float*)alloc(13 * 64 * 4);
    float* bfold = (float*)alloc(64 * 4);
    _Float16* WlT16 = (_Float16*)alloc(4 * 4096 * 2);
    _Float16* nodeWi = (_Float16*)alloc((size_t)N_NODES * 64 * 2);
    _Float16* h = (_Float16*)alloc((size_t)N_EDGES * 64 * 2);
    _Float16* agg = (_Float16*)alloc((size_t)N_NODES * 64 * 2);
    float* g = (float*)alloc((size_t)N_GRAPHS * 64 * 4);

    hipLaunchKernelGGL(k_fold, dim3(1), dim3(64), 0, stream, We, be, Wi, bi, Wl,
                       WeWi, bfold, WlT16);
    hipLaunchKernelGGL(k_node, dim3(N_NODES / 64), dim3(256), 0, stream, nf, Wn, bn, Wi, nodeWi);
    hipLaunchKernelGGL(k_h0, dim3(N_EDGES / 64), dim3(256), 0, stream, ef, src, WeWi, bfold,
                       nodeWi, h);

    for (int l = 0; l < 4; l++) {
        hipMemsetAsync(agg, 0, (size_t)N_NODES * 64 * 2, stream);
        hipLaunchKernelGGL(k_scatter, dim3(N_EDGES * 32 / 256), dim3(256), 0, stream,
                           (const __half2*)h, dst, (__half2*)agg);
        hipLaunchKernelGGL(k_conv, dim3(N_EDGES / 64), dim3(256), 0, stream, agg, h, nodeWi,
                           ef, src, WeWi, bfold, WlT16, bl, l);
    }
    hipMemsetAsync(agg, 0, (size_t)N_NODES * 64 * 2, stream);
    hipLaunchKernelGGL(k_scatter, dim3(N_EDGES * 32 / 256), dim3(256), 0, stream,
                       (const __half2*)h, dst, (__half2*)agg);
    hipMemsetAsync(g, 0, (size_t)N_GRAPHS * 64 * 4, stream);
    hipLaunchKernelGGL(k_nodeout, dim3(N_NODES / 64), dim3(256), 0, stream, nf, Wn, bn, agg,
                       Wa, ba, gid, g);
    hipLaunchKernelGGL(k_head, dim3(N_GRAPHS / 4), dim3(256), 0, stream, g, W1, b1, W2, b2,
                       (float*)d_out);
}

// Round 5
// 2538.566 us; speedup vs baseline: 1.8256x; 1.4816x over previous
//
#include <hip/hip_runtime.h>
#include <hip/hip_fp16.h>
#include <stdint.h>

#define N_NODES 400000
#define N_EDGES 1600000
#define N_GRAPHS 10000
#define SLOPE 0.01f

typedef _Float16 hf4 __attribute__((ext_vector_type(4)));
typedef _Float16 hf8 __attribute__((ext_vector_type(8)));
typedef float f32x4 __attribute__((ext_vector_type(4)));

__device__ __forceinline__ float lrelu(float x) { return x > 0.f ? x : SLOPE * x; }

// ---------------------------------------------------------------------------
// Host-side weight preprocessing, all in one tiny kernel (64 threads):
//  WeWi[13][64]  = We @ Wi_bot          bfold = bi + be @ Wi_bot
//  WlT16[l][j][k] = fp16 Wl[l][k][j]
//  WTn[j][d]     = fp16 (Wn @ Wi_top)[d][j]   (d<74; 74..95 zero)   bnWi = bn @ Wi_top
//  WTo[j][d]     = fp16 (Wn @ Wa_top)[d][j] (d<74) | Wa_bot[d-80][j] (80<=d<144) | 0
//  bna           = ba + bn @ Wa_top
__global__ void k_fold(const float* We, const float* be, const float* Wi, const float* bi,
                       const float* Wn, const float* bn, const float* Wa, const float* ba,
                       const float* Wl, float* WeWi, float* bfold, _Float16* WlT16,
                       _Float16* WTn, float* bnWi, _Float16* WTo, float* bna) {
    int j = threadIdx.x;  // 64 threads
    for (int d = 0; d < 13; d++) {
        float acc = 0.f;
        for (int k = 0; k < 64; k++) acc += We[d * 64 + k] * Wi[(64 + k) * 64 + j];
        WeWi[d * 64 + j] = acc;
    }
    float accb = bi[j];
    for (int k = 0; k < 64; k++) accb += be[k] * Wi[(64 + k) * 64 + j];
    bfold[j] = accb;
    for (int l = 0; l < 4; l++)
        for (int k = 0; k < 64; k++)
            WlT16[l * 4096 + j * 64 + k] = (_Float16)Wl[l * 4096 + k * 64 + j];
    for (int d = 0; d < 96; d++) {
        float acc = 0.f;
        if (d < 74)
            for (int k = 0; k < 64; k++) acc += Wn[d * 64 + k] * Wi[k * 64 + j];
        WTn[j * 96 + d] = (_Float16)acc;
    }
    {
        float acc = 0.f;
        for (int k = 0; k < 64; k++) acc += bn[k] * Wi[k * 64 + j];
        bnWi[j] = acc;
    }
    for (int d = 0; d < 160; d++) {
        float acc = 0.f;
        if (d < 74)
            for (int k = 0; k < 64; k++) acc += Wn[d * 64 + k] * Wa[k * 64 + j];
        else if (d >= 80 && d < 144)
            acc = Wa[(64 + d - 80) * 64 + j];
        WTo[j * 160 + d] = (_Float16)acc;
    }
    {
        float acc = ba[j];
        for (int k = 0; k < 64; k++) acc += bn[k] * Wa[k * 64 + j];
        bna[j] = acc;
    }
}

// ---------------------------------------------------------------------------
// nodeWi = nf @ WnWi + bnWi   (MFMA, fp16 out)
__global__ __launch_bounds__(256) void k_node(const float* nf, const _Float16* WTn,
                                              const float* bnWi, _Float16* nodeWi) {
    __shared__ __align__(16) _Float16 A[64 * 104];
    __shared__ __align__(16) _Float16 WT[64 * 104];
    int t = threadIdx.x;
    int n0 = blockIdx.x * 64;
    for (int idx = t; idx < 64 * 96; idx += 256) {
        int r = idx / 96, c = idx % 96;
        float v = (c < 74) ? nf[(size_t)(n0 + r) * 74 + c] : 0.f;
        A[r * 104 + c] = (_Float16)v;
    }
    for (int idx = t; idx < 64 * 24; idx += 256) {
        int r = idx / 24, c4 = idx % 24;
        *(hf4*)&WT[r * 104 + c4 * 4] = *(const hf4*)(WTn + r * 96 + c4 * 4);
    }
    __syncthreads();
    int lane = t & 63, w = t >> 6;
    int m16 = lane & 15, quad = lane >> 4;
    f32x4 acc[4];
#pragma unroll
    for (int jt = 0; jt < 4; jt++) acc[jt] = (f32x4){0.f, 0.f, 0.f, 0.f};
#pragma unroll
    for (int kt = 0; kt < 3; kt++) {
        hf8 a = *(const hf8*)&A[(w * 16 + m16) * 104 + kt * 32 + quad * 8];
#pragma unroll
        for (int jt = 0; jt < 4; jt++) {
            hf8 b = *(const hf8*)&WT[(jt * 16 + m16) * 104 + kt * 32 + quad * 8];
            acc[jt] = __builtin_amdgcn_mfma_f32_16x16x32_f16(a, b, acc[jt], 0, 0, 0);
        }
    }
#pragma unroll
    for (int jt = 0; jt < 4; jt++) {
        int col = jt * 16 + m16;
        float bb = bnWi[col];
#pragma unroll
        for (int r = 0; r < 4; r++) {
            int row = w * 16 + quad * 4 + r;
            nodeWi[(size_t)(n0 + row) * 64 + col] = (_Float16)(acc[jt][r] + bb);
        }
    }
}

// ---------------------------------------------------------------------------
// h = lrelu(nodeWi[src] + ef @ WeWi + bfold); fused scatter: agg[dst] += h
__global__ __launch_bounds__(256) void k_h0(const float* ef, const int* src, const int* dst,
                                            const float* WeWi, const float* bfold,
                                            const _Float16* nodeWi, _Float16* h,
                                            __half2* agg2) {
    __shared__ float efL[832];
    __shared__ float WW[832];
    __shared__ float bf[64];
    __shared__ int dstL[64];
    int t = threadIdx.x;
    int e0 = blockIdx.x * 64;
    for (int v = t; v < 832; v += 256) efL[v] = ef[(size_t)e0 * 13 + v];
    for (int v = t; v < 832; v += 256) WW[v] = WeWi[v];
    if (t < 64) { bf[t] = bfold[t]; dstL[t] = dst[e0 + t]; }
    __syncthreads();
    int j = t & 63, sub = t >> 6;
    for (int i = 0; i < 16; i++) {
        int el = sub + 4 * i;
        int e = e0 + el;
        float acc = bf[j];
        for (int d = 0; d < 13; d++) acc += efL[el * 13 + d] * WW[d * 64 + j];
        acc += (float)nodeWi[(size_t)src[e] * 64 + j];
        float v = lrelu(acc);
        h[(size_t)e * 64 + j] = (_Float16)v;
        float vn = __shfl_down(v, 1, 64);
        if ((j & 1) == 0) {
            __half2 p = __halves2half2(__float2half(v), __float2half(vn));
            unsafeAtomicAdd(&agg2[(size_t)dstL[el] * 32 + (j >> 1)], p);
        }
    }
}

// ---------------------------------------------------------------------------
// h = lrelu(h0 + (agg[src] - h[rev]) @ Wl[l] + bl[l])  IN-PLACE on h, with
// h0 recomputed (nodeWi[src] + ef@WeWi + bfold) and fused scatter into
// aggN[dst] += h_new.  MFMA GEMM, C round-trips through LDS (union region).
__global__ __launch_bounds__(256) void k_conv(const _Float16* agg, _Float16* h,
                                              const _Float16* nodeWi, const float* ef,
                                              const int* src, const int* dst,
                                              const float* WeWi, const float* bfold,
                                              const _Float16* WlT16, const float* bl_g,
                                              int layer, __half2* aggN2) {
    __shared__ __align__(16) char uni[18432];
    _Float16* Msh = (_Float16*)uni;           // [64][72] fp16 (phase A/B)
    _Float16* WTs = (_Float16*)(uni + 9216);  // [64][72] fp16 (phase A/B)
    float* Cs = (float*)uni;                  // [64][65] fp32 (phase C/D)
    __shared__ float efL[832];
    __shared__ float WWL[832];
    __shared__ float bfL[64];
    __shared__ int srcL[64];
    __shared__ int dstL[64];
    int t = threadIdx.x;
    int e0 = blockIdx.x * 64;
    const _Float16* WTg = WlT16 + layer * 4096;
    for (int i = 0; i < 4; i++) {
        int idx = t + 256 * i;  // 0..1023
        int r = idx >> 4, c4 = idx & 15;
        *(hf4*)&WTs[r * 72 + c4 * 4] = *(const hf4*)(WTg + r * 64 + c4 * 4);
    }
    for (int i = 0; i < 4; i++) {
        int idx = t + 256 * i;
        int e = idx >> 4, k4 = idx & 15;
        int ge = e0 + e;
        int s = src[ge];
        hf4 av = *(const hf4*)(agg + (size_t)s * 64 + k4 * 4);
        hf4 hv = *(const hf4*)(h + (size_t)(ge ^ 1) * 64 + k4 * 4);
        hf4 m;
        m.x = av.x - hv.x; m.y = av.y - hv.y; m.z = av.z - hv.z; m.w = av.w - hv.w;
        *(hf4*)&Msh[e * 72 + k4 * 4] = m;
    }
    for (int v = t; v < 832; v += 256) efL[v] = ef[(size_t)e0 * 13 + v];
    for (int v = t; v < 832; v += 256) WWL[v] = WeWi[v];
    if (t < 64) { bfL[t] = bfold[t]; srcL[t] = src[e0 + t]; dstL[t] = dst[e0 + t]; }
    __syncthreads();
    int lane = t & 63, w = t >> 6;
    int m16 = lane & 15, quad = lane >> 4;
    f32x4 acc[4];
#pragma unroll
    for (int jt = 0; jt < 4; jt++) acc[jt] = (f32x4){0.f, 0.f, 0.f, 0.f};
#pragma unroll
    for (int kt = 0; kt < 2; kt++) {
        hf8 a = *(const hf8*)&Msh[(w * 16 + m16) * 72 + kt * 32 + quad * 8];
#pragma unroll
        for (int jt = 0; jt < 4; jt++) {
            hf8 b = *(const hf8*)&WTs[(jt * 16 + m16) * 72 + kt * 32 + quad * 8];
            acc[jt] = __builtin_amdgcn_mfma_f32_16x16x32_f16(a, b, acc[jt], 0, 0, 0);
        }
    }
    __syncthreads();
#pragma unroll
    for (int jt = 0; jt < 4; jt++)
#pragma unroll
        for (int r = 0; r < 4; r++)
            Cs[(w * 16 + quad * 4 + r) * 65 + jt * 16 + m16] = acc[jt][r];
    __syncthreads();
    int j = t & 63, sub = t >> 6;
    float blj = bl_g[layer * 64 + j];
    float bfj = bfL[j];
    for (int i = 0; i < 16; i++) {
        int el = sub + 4 * i;
        int ge = e0 + el;
        int s = srcL[el];
        float z = bfj + (float)nodeWi[(size_t)s * 64 + j];
        const float* er = &efL[el * 13];
#pragma unroll
        for (int d = 0; d < 13; d++) z += er[d] * WWL[d * 64 + j];
        float val = lrelu(lrelu(z) + Cs[el * 65 + j] + blj);
        h[(size_t)ge * 64 + j] = (_Float16)val;
        float vn = __shfl_down(val, 1, 64);
        if ((j & 1) == 0) {
            __half2 p = __halves2half2(__float2half(val), __float2half(vn));
            unsafeAtomicAdd(&aggN2[(size_t)dstL[el] * 32 + (j >> 1)], p);
        }
    }
}

// ---------------------------------------------------------------------------
// z = nf @ Wna + agg @ Wab + bna (MFMA, K=160); g[gid] += lrelu(z)
__global__ __launch_bounds__(256) void k_nodeout(const float* nf, const _Float16* agg,
                                                 const _Float16* WTo, const float* bna,
                                                 const int* gidp, float* g) {
    __shared__ __align__(16) _Float16 A[64 * 168];
    __shared__ __align__(16) _Float16 WT[64 * 168];
    int t = threadIdx.x;
    int n0 = blockIdx.x * 64;
    for (int idx = t; idx < 64 * 80; idx += 256) {
        int r = idx / 80, c = idx % 80;
        float v = (c < 74) ? nf[(size_t)(n0 + r) * 74 + c] : 0.f;
        A[r * 168 + c] = (_Float16)v;
    }
    for (int idx = t; idx < 64 * 16; idx += 256) {
        int r = idx >> 4, c4 = idx & 15;
        *(hf4*)&A[r * 168 + 80 + c4 * 4] = *(const hf4*)(agg + (size_t)(n0 + r) * 64 + c4 * 4);
    }
    for (int idx = t; idx < 64 * 16; idx += 256) {
        int r = idx >> 4, c = idx & 15;
        A[r * 168 + 144 + c] = (_Float16)0.f;
    }
    for (int idx = t; idx < 64 * 40; idx += 256) {
        int r = idx / 40, c4 = idx % 40;
        *(hf4*)&WT[r * 168 + c4 * 4] = *(const hf4*)(WTo + r * 160 + c4 * 4);
    }
    __syncthreads();
    int lane = t & 63, w = t >> 6;
    int m16 = lane & 15, quad = lane >> 4;
    f32x4 acc[4];
#pragma unroll
    for (int jt = 0; jt < 4; jt++) acc[jt] = (f32x4){0.f, 0.f, 0.f, 0.f};
#pragma unroll
    for (int kt = 0; kt < 5; kt++) {
        hf8 a = *(const hf8*)&A[(w * 16 + m16) * 168 + kt * 32 + quad * 8];
#pragma unroll
        for (int jt = 0; jt < 4; jt++) {
            hf8 b = *(const hf8*)&WT[(jt * 16 + m16) * 168 + kt * 32 + quad * 8];
            acc[jt] = __builtin_amdgcn_mfma_f32_16x16x32_f16(a, b, acc[jt], 0, 0, 0);
        }
    }
#pragma unroll
    for (int jt = 0; jt < 4; jt++) {
        int col = jt * 16 + m16;
        float bb = bna[col];
#pragma unroll
        for (int r = 0; r < 4; r++) {
            int row = w * 16 + quad * 4 + r;
            float v = lrelu(acc[jt][r] + bb);
            atomicAdd(&g[(size_t)gidp[n0 + row] * 64 + col], v);
        }
    }
}

// ---------------------------------------------------------------------------
// out = lrelu(g @ W1 + b1) @ W2 + b2   (one wave per graph)
__global__ __launch_bounds__(256) void k_head(const float* g, const float* W1,
                                              const float* b1, const float* W2,
                                              const float* b2, float* out) {
    __shared__ float W1L[4096];
    int t = threadIdx.x;
    for (int v = t; v < 4096; v += 256) W1L[v] = W1[v];
    __syncthreads();
    int w = t >> 6, j = t & 63;
    int graph = blockIdx.x * 4 + w;
    if (graph >= N_GRAPHS) return;
    const float* gr = g + (size_t)graph * 64;
    float acc = b1[j];
    for (int k = 0; k < 64; k++) acc += gr[k] * W1L[k * 64 + j];
    float p = lrelu(acc) * W2[j];
    for (int off = 32; off > 0; off >>= 1) p += __shfl_down(p, off, 64);
    if (j == 0) out[graph] = p + b2[0];
}

// ---------------------------------------------------------------------------
extern "C" void kernel_launch(void* const* d_in, const int* in_sizes, int n_in,
                              void* d_out, int out_size, void* d_ws, size_t ws_size,
                              hipStream_t stream) {
    const float* nf = (const float*)d_in[0];
    const float* ef = (const float*)d_in[1];
    const int* src = (const int*)d_in[2];
    const int* dst = (const int*)d_in[3];
    const int* gid = (const int*)d_in[4];
    const float* Wn = (const float*)d_in[5];
    const float* bn = (const float*)d_in[6];
    const float* We = (const float*)d_in[7];
    const float* be = (const float*)d_in[8];
    const float* Wi = (const float*)d_in[9];
    const float* bi = (const float*)d_in[10];
    const float* Wa = (const float*)d_in[11];
    const float* ba = (const float*)d_in[12];
    const float* Wl = (const float*)d_in[13];
    const float* bl = (const float*)d_in[14];
    const float* W1 = (const float*)d_in[15];
    const float* b1 = (const float*)d_in[16];
    const float* W2 = (const float*)d_in[17];
    const float* b2 = (const float*)d_in[18];

    char* ws = (char*)d_ws;
    size_t off = 0;
    auto alloc = [&](size_t bytes) -> char* {
        char* p = ws + off;
        off += (bytes + 255) & ~(size_t)255;
        return p;
    };
    // total ~344 MiB
    float* WeWi = (float*)alloc(13 * 64 * 4);
    float* bfold = (float*)alloc(64 * 4);
    _Float16* WlT16 = (_Float16*)alloc(4 * 4096 * 2);
    _Float16* WTn = (_Float16*)alloc(64 * 96 * 2);
    float* bnWi = (float*)alloc(64 * 4);
    _Float16* WTo = (_Float16*)alloc(64 * 160 * 2);
    float* bna = (float*)alloc(64 * 4);
    _Float16* nodeWi = (_Float16*)alloc((size_t)N_NODES * 64 * 2);
    _Float16* h = (_Float16*)alloc((size_t)N_EDGES * 64 * 2);
    _Float16* aggA = (_Float16*)alloc((size_t)N_NODES * 64 * 2);
    _Float16* aggB = (_Float16*)alloc((size_t)N_NODES * 64 * 2);
    float* g = (float*)alloc((size_t)N_GRAPHS * 64 * 4);

    hipLaunchKernelGGL(k_fold, dim3(1), dim3(64), 0, stream, We, be, Wi, bi, Wn, bn, Wa, ba,
                       Wl, WeWi, bfold, WlT16, WTn, bnWi, WTo, bna);
    hipLaunchKernelGGL(k_node, dim3(N_NODES / 64), dim3(256), 0, stream, nf, WTn, bnWi, nodeWi);
    hipMemsetAsync(aggA, 0, (size_t)N_NODES * 64 * 2, stream);
    hipLaunchKernelGGL(k_h0, dim3(N_EDGES / 64), dim3(256), 0, stream, ef, src, dst, WeWi,
                       bfold, nodeWi, h, (__half2*)aggA);

    _Float16* cur = aggA;
    _Float16* nxt = aggB;
    for (int l = 0; l < 4; l++) {
        hipMemsetAsync(nxt, 0, (size_t)N_NODES * 64 * 2, stream);
        hipLaunchKernelGGL(k_conv, dim3(N_EDGES / 64), dim3(256), 0, stream, cur, h, nodeWi,
                           ef, src, dst, WeWi, bfold, WlT16, bl, l, (__half2*)nxt);
        _Float16* tmp = cur; cur = nxt; nxt = tmp;
    }
    hipMemsetAsync(g, 0, (size_t)N_GRAPHS * 64 * 4, stream);
    hipLaunchKernelGGL(k_nodeout, dim3(N_NODES / 64), dim3(256), 0, stream, nf, cur, WTo, bna,
                       gid, g);
    hipLaunchKernelGGL(k_head, dim3(N_GRAPHS / 4), dim3(256), 0, stream, g, W1, b1, W2, b2,
                       (float*)d_out);
}

// Round 6
// 2415.788 us; speedup vs baseline: 1.9184x; 1.0508x over previous
//
#include <hip/hip_runtime.h>
#include <hip/hip_fp16.h>
#include <stdint.h>

#define N_NODES 400000
#define N_EDGES 1600000
#define N_GRAPHS 10000
#define SLOPE 0.01f

typedef _Float16 hf4 __attribute__((ext_vector_type(4)));
typedef _Float16 hf8 __attribute__((ext_vector_type(8)));
typedef float f32x4 __attribute__((ext_vector_type(4)));

__device__ __forceinline__ float lrelu(float x) { return x > 0.f ? x : SLOPE * x; }

// ---------------------------------------------------------------------------
// Weight preprocessing (one 64-thread block):
//  WeWi[13][64]  = We @ Wi_bot          bfold = bi + be @ Wi_bot
//  WlT16[l][j][k] = fp16 Wl[l][k][j]
//  WTn[j][d]     = fp16 (Wn @ Wi_top)[d][j]   (d<74; 74..95 zero)   bnWi = bn @ Wi_top
//  WTo[j][d]     = fp16 (Wn @ Wa_top)[d][j] (d<74) | Wa_bot[d-80][j] (80<=d<144) | 0
//  bna           = ba + bn @ Wa_top
__global__ void k_fold(const float* We, const float* be, const float* Wi, const float* bi,
                       const float* Wn, const float* bn, const float* Wa, const float* ba,
                       const float* Wl, float* WeWi, float* bfold, _Float16* WlT16,
                       _Float16* WTn, float* bnWi, _Float16* WTo, float* bna) {
    int j = threadIdx.x;  // 64 threads
    for (int d = 0; d < 13; d++) {
        float acc = 0.f;
        for (int k = 0; k < 64; k++) acc += We[d * 64 + k] * Wi[(64 + k) * 64 + j];
        WeWi[d * 64 + j] = acc;
    }
    float accb = bi[j];
    for (int k = 0; k < 64; k++) accb += be[k] * Wi[(64 + k) * 64 + j];
    bfold[j] = accb;
    for (int l = 0; l < 4; l++)
        for (int k = 0; k < 64; k++)
            WlT16[l * 4096 + j * 64 + k] = (_Float16)Wl[l * 4096 + k * 64 + j];
    for (int d = 0; d < 96; d++) {
        float acc = 0.f;
        if (d < 74)
            for (int k = 0; k < 64; k++) acc += Wn[d * 64 + k] * Wi[k * 64 + j];
        WTn[j * 96 + d] = (_Float16)acc;
    }
    {
        float acc = 0.f;
        for (int k = 0; k < 64; k++) acc += bn[k] * Wi[k * 64 + j];
        bnWi[j] = acc;
    }
    for (int d = 0; d < 160; d++) {
        float acc = 0.f;
        if (d < 74)
            for (int k = 0; k < 64; k++) acc += Wn[d * 64 + k] * Wa[k * 64 + j];
        else if (d >= 80 && d < 144)
            acc = Wa[(64 + d - 80) * 64 + j];
        WTo[j * 160 + d] = (_Float16)acc;
    }
    {
        float acc = ba[j];
        for (int k = 0; k < 64; k++) acc += bn[k] * Wa[k * 64 + j];
        bna[j] = acc;
    }
}

// ---------------------------------------------------------------------------
// nodeWi = nf @ WnWi + bnWi   (MFMA, fp16 out)
__global__ __launch_bounds__(256) void k_node(const float* nf, const _Float16* WTn,
                                              const float* bnWi, _Float16* nodeWi) {
    __shared__ __align__(16) _Float16 A[64 * 104];
    __shared__ __align__(16) _Float16 WT[64 * 104];
    int t = threadIdx.x;
    int n0 = blockIdx.x * 64;
    for (int idx = t; idx < 64 * 96; idx += 256) {
        int r = idx / 96, c = idx % 96;
        float v = (c < 74) ? nf[(size_t)(n0 + r) * 74 + c] : 0.f;
        A[r * 104 + c] = (_Float16)v;
    }
    for (int idx = t; idx < 64 * 24; idx += 256) {
        int r = idx / 24, c4 = idx % 24;
        *(hf4*)&WT[r * 104 + c4 * 4] = *(const hf4*)(WTn + r * 96 + c4 * 4);
    }
    __syncthreads();
    int lane = t & 63, w = t >> 6;
    int m16 = lane & 15, quad = lane >> 4;
    f32x4 acc[4];
#pragma unroll
    for (int jt = 0; jt < 4; jt++) acc[jt] = (f32x4){0.f, 0.f, 0.f, 0.f};
#pragma unroll
    for (int kt = 0; kt < 3; kt++) {
        hf8 a = *(const hf8*)&A[(w * 16 + m16) * 104 + kt * 32 + quad * 8];
#pragma unroll
        for (int jt = 0; jt < 4; jt++) {
            hf8 b = *(const hf8*)&WT[(jt * 16 + m16) * 104 + kt * 32 + quad * 8];
            acc[jt] = __builtin_amdgcn_mfma_f32_16x16x32_f16(a, b, acc[jt], 0, 0, 0);
        }
    }
#pragma unroll
    for (int jt = 0; jt < 4; jt++) {
        int col = jt * 16 + m16;
        float bb = bnWi[col];
#pragma unroll
        for (int r = 0; r < 4; r++) {
            int row = w * 16 + quad * 4 + r;
            nodeWi[(size_t)(n0 + row) * 64 + col] = (_Float16)(acc[jt][r] + bb);
        }
    }
}

// ---------------------------------------------------------------------------
// h = lrelu(nodeWi[src] + ef @ WeWi + bfold); fused scatter: agg[dst] += h
// nodeWi gathers register-prefetched at kernel start (issue-parallel).
__global__ __launch_bounds__(256) void k_h0(const float* ef, const int* src, const int* dst,
                                            const float* WeWi, const float* bfold,
                                            const _Float16* nodeWi, _Float16* h,
                                            __half2* agg2) {
    __shared__ float efL[832];
    __shared__ float WW[832];
    __shared__ float bf[64];
    __shared__ int dstL[64];
    int t = threadIdx.x;
    int e0 = blockIdx.x * 64;
    int j = t & 63, sub = t >> 6;
    int sv[16];
#pragma unroll
    for (int i = 0; i < 16; i++) sv[i] = src[e0 + sub + 4 * i];
    _Float16 nwv[16];
#pragma unroll
    for (int i = 0; i < 16; i++) nwv[i] = nodeWi[(size_t)sv[i] * 64 + j];
    for (int v = t; v < 832; v += 256) efL[v] = ef[(size_t)e0 * 13 + v];
    for (int v = t; v < 832; v += 256) WW[v] = WeWi[v];
    if (t < 64) { bf[t] = bfold[t]; dstL[t] = dst[e0 + t]; }
    __syncthreads();
    float bfj = bf[j];
#pragma unroll
    for (int i = 0; i < 16; i++) {
        int el = sub + 4 * i;
        int e = e0 + el;
        float acc = bfj + (float)nwv[i];
        const float* er = &efL[el * 13];
#pragma unroll
        for (int d = 0; d < 13; d++) acc += er[d] * WW[d * 64 + j];
        float v = lrelu(acc);
        h[(size_t)e * 64 + j] = (_Float16)v;
        float vn = __shfl_down(v, 1, 64);
        if ((j & 1) == 0) {
            __half2 p = __halves2half2(__float2half(v), __float2half(vn));
            unsafeAtomicAdd(&agg2[(size_t)dstL[el] * 32 + (j >> 1)], p);
        }
    }
}

// ---------------------------------------------------------------------------
// h = lrelu(h0 + (agg[src] - h[rev]) @ Wl[l] + bl[l])  IN-PLACE on h, with
// h0 recomputed (nodeWi[src] + ef@WeWi + bfold) and fused scatter into
// aggN[dst] += h_new.  MFMA GEMM, C round-trips through LDS (union region).
// nodeWi gathers register-prefetched in phase A, consumed in phase D —
// latency hidden behind the MFMA + LDS phases.
__global__ __launch_bounds__(256) void k_conv(const _Float16* agg, _Float16* h,
                                              const _Float16* nodeWi, const float* ef,
                                              const int* src, const int* dst,
                                              const float* WeWi, const float* bfold,
                                              const _Float16* WlT16, const float* bl_g,
                                              int layer, __half2* aggN2) {
    __shared__ __align__(16) char uni[18432];
    _Float16* Msh = (_Float16*)uni;           // [64][72] fp16 (phase A/B)
    _Float16* WTs = (_Float16*)(uni + 9216);  // [64][72] fp16 (phase A/B)
    float* Cs = (float*)uni;                  // [64][65] fp32 (phase C/D)
    __shared__ float efL[832];
    __shared__ float WWL[832];
    __shared__ float bfL[64];
    __shared__ int dstL[64];
    int t = threadIdx.x;
    int e0 = blockIdx.x * 64;
    int j = t & 63, sub = t >> 6;
    const _Float16* WTg = WlT16 + layer * 4096;
    // --- phase A: stage WT, M; prefetch nodeWi rows into registers ---
    int sv[16];
#pragma unroll
    for (int i = 0; i < 16; i++) sv[i] = src[e0 + sub + 4 * i];
    _Float16 nwv[16];
#pragma unroll
    for (int i = 0; i < 16; i++) nwv[i] = nodeWi[(size_t)sv[i] * 64 + j];
    for (int i = 0; i < 4; i++) {
        int idx = t + 256 * i;  // 0..1023
        int r = idx >> 4, c4 = idx & 15;
        *(hf4*)&WTs[r * 72 + c4 * 4] = *(const hf4*)(WTg + r * 64 + c4 * 4);
    }
    for (int i = 0; i < 4; i++) {
        int idx = t + 256 * i;
        int e = idx >> 4, k4 = idx & 15;
        int ge = e0 + e;
        int s = src[ge];
        hf4 av = *(const hf4*)(agg + (size_t)s * 64 + k4 * 4);
        hf4 hv = *(const hf4*)(h + (size_t)(ge ^ 1) * 64 + k4 * 4);
        hf4 m;
        m.x = av.x - hv.x; m.y = av.y - hv.y; m.z = av.z - hv.z; m.w = av.w - hv.w;
        *(hf4*)&Msh[e * 72 + k4 * 4] = m;
    }
    for (int v = t; v < 832; v += 256) efL[v] = ef[(size_t)e0 * 13 + v];
    for (int v = t; v < 832; v += 256) WWL[v] = WeWi[v];
    if (t < 64) { bfL[t] = bfold[t]; dstL[t] = dst[e0 + t]; }
    __syncthreads();
    // --- phase B: MFMA ---
    int lane = t & 63, w = t >> 6;
    int m16 = lane & 15, quad = lane >> 4;
    f32x4 acc[4];
#pragma unroll
    for (int jt = 0; jt < 4; jt++) acc[jt] = (f32x4){0.f, 0.f, 0.f, 0.f};
#pragma unroll
    for (int kt = 0; kt < 2; kt++) {
        hf8 a = *(const hf8*)&Msh[(w * 16 + m16) * 72 + kt * 32 + quad * 8];
#pragma unroll
        for (int jt = 0; jt < 4; jt++) {
            hf8 b = *(const hf8*)&WTs[(jt * 16 + m16) * 72 + kt * 32 + quad * 8];
            acc[jt] = __builtin_amdgcn_mfma_f32_16x16x32_f16(a, b, acc[jt], 0, 0, 0);
        }
    }
    __syncthreads();
    // --- phase C: C -> LDS (C layout: col=lane&15, row=quad*4+reg) ---
#pragma unroll
    for (int jt = 0; jt < 4; jt++)
#pragma unroll
        for (int r = 0; r < 4; r++)
            Cs[(w * 16 + quad * 4 + r) * 65 + jt * 16 + m16] = acc[jt][r];
    __syncthreads();
    // --- phase D: epilogue, coalesced column-per-thread + fused scatter ---
    float blj = bl_g[layer * 64 + j];
    float bfj = bfL[j];
#pragma unroll
    for (int i = 0; i < 16; i++) {
        int el = sub + 4 * i;
        int ge = e0 + el;
        float z = bfj + (float)nwv[i];
        const float* er = &efL[el * 13];
#pragma unroll
        for (int d = 0; d < 13; d++) z += er[d] * WWL[d * 64 + j];
        float val = lrelu(lrelu(z) + Cs[el * 65 + j] + blj);
        h[(size_t)ge * 64 + j] = (_Float16)val;
        float vn = __shfl_down(val, 1, 64);
        if ((j & 1) == 0) {
            __half2 p = __halves2half2(__float2half(val), __float2half(vn));
            unsafeAtomicAdd(&aggN2[(size_t)dstL[el] * 32 + (j >> 1)], p);
        }
    }
}

// ---------------------------------------------------------------------------
// z = nf @ Wna + agg @ Wab + bna (MFMA, K=160); g[gid] += lrelu(z)
__global__ __launch_bounds__(256) void k_nodeout(const float* nf, const _Float16* agg,
                                                 const _Float16* WTo, const float* bna,
                                                 const int* gidp, float* g) {
    __shared__ __align__(16) _Float16 A[64 * 168];
    __shared__ __align__(16) _Float16 WT[64 * 168];
    int t = threadIdx.x;
    int n0 = blockIdx.x * 64;
    for (int idx = t; idx < 64 * 80; idx += 256) {
        int r = idx / 80, c = idx % 80;
        float v = (c < 74) ? nf[(size_t)(n0 + r) * 74 + c] : 0.f;
        A[r * 168 + c] = (_Float16)v;
    }
    for (int idx = t; idx < 64 * 16; idx += 256) {
        int r = idx >> 4, c4 = idx & 15;
        *(hf4*)&A[r * 168 + 80 + c4 * 4] = *(const hf4*)(agg + (size_t)(n0 + r) * 64 + c4 * 4);
    }
    for (int idx = t; idx < 64 * 16; idx += 256) {
        int r = idx >> 4, c = idx & 15;
        A[r * 168 + 144 + c] = (_Float16)0.f;
    }
    for (int idx = t; idx < 64 * 40; idx += 256) {
        int r = idx / 40, c4 = idx % 40;
        *(hf4*)&WT[r * 168 + c4 * 4] = *(const hf4*)(WTo + r * 160 + c4 * 4);
    }
    __syncthreads();
    int lane = t & 63, w = t >> 6;
    int m16 = lane & 15, quad = lane >> 4;
    f32x4 acc[4];
#pragma unroll
    for (int jt = 0; jt < 4; jt++) acc[jt] = (f32x4){0.f, 0.f, 0.f, 0.f};
#pragma unroll
    for (int kt = 0; kt < 5; kt++) {
        hf8 a = *(const hf8*)&A[(w * 16 + m16) * 168 + kt * 32 + quad * 8];
#pragma unroll
        for (int jt = 0; jt < 4; jt++) {
            hf8 b = *(const hf8*)&WT[(jt * 16 + m16) * 168 + kt * 32 + quad * 8];
            acc[jt] = __builtin_amdgcn_mfma_f32_16x16x32_f16(a, b, acc[jt], 0, 0, 0);
        }
    }
#pragma unroll
    for (int jt = 0; jt < 4; jt++) {
        int col = jt * 16 + m16;
        float bb = bna[col];
#pragma unroll
        for (int r = 0; r < 4; r++) {
            int row = w * 16 + quad * 4 + r;
            float v = lrelu(acc[jt][r] + bb);
            atomicAdd(&g[(size_t)gidp[n0 + row] * 64 + col], v);
        }
    }
}

// ---------------------------------------------------------------------------
// out = lrelu(g @ W1 + b1) @ W2 + b2   (one wave per graph)
__global__ __launch_bounds__(256) void k_head(const float* g, const float* W1,
                                              const float* b1, const float* W2,
                                              const float* b2, float* out) {
    __shared__ float W1L[4096];
    int t = threadIdx.x;
    for (int v = t; v < 4096; v += 256) W1L[v] = W1[v];
    __syncthreads();
    int w = t >> 6, j = t & 63;
    int graph = blockIdx.x * 4 + w;
    if (graph >= N_GRAPHS) return;
    const float* gr = g + (size_t)graph * 64;
    float acc = b1[j];
    for (int k = 0; k < 64; k++) acc += gr[k] * W1L[k * 64 + j];
    float p = lrelu(acc) * W2[j];
    for (int off = 32; off > 0; off >>= 1) p += __shfl_down(p, off, 64);
    if (j == 0) out[graph] = p + b2[0];
}

// ---------------------------------------------------------------------------
extern "C" void kernel_launch(void* const* d_in, const int* in_sizes, int n_in,
                              void* d_out, int out_size, void* d_ws, size_t ws_size,
                              hipStream_t stream) {
    const float* nf = (const float*)d_in[0];
    const float* ef = (const float*)d_in[1];
    const int* src = (const int*)d_in[2];
    const int* dst = (const int*)d_in[3];
    const int* gid = (const int*)d_in[4];
    const float* Wn = (const float*)d_in[5];
    const float* bn = (const float*)d_in[6];
    const float* We = (const float*)d_in[7];
    const float* be = (const float*)d_in[8];
    const float* Wi = (const float*)d_in[9];
    const float* bi = (const float*)d_in[10];
    const float* Wa = (const float*)d_in[11];
    const float* ba = (const float*)d_in[12];
    const float* Wl = (const float*)d_in[13];
    const float* bl = (const float*)d_in[14];
    const float* W1 = (const float*)d_in[15];
    const float* b1 = (const float*)d_in[16];
    const float* W2 = (const float*)d_in[17];
    const float* b2 = (const float*)d_in[18];

    char* ws = (char*)d_ws;
    size_t off = 0;
    auto alloc = [&](size_t bytes) -> char* {
        char* p = ws + off;
        off += (bytes + 255) & ~(size_t)255;
        return p;
    };
    // total ~344 MiB
    float* WeWi = (float*)alloc(13 * 64 * 4);
    float* bfold = (float*)alloc(64 * 4);
    _Float16* WlT16 = (_Float16*)alloc(4 * 4096 * 2);
    _Float16* WTn = (_Float16*)alloc(64 * 96 * 2);
    float* bnWi = (float*)alloc(64 * 4);
    _Float16* WTo = (_Float16*)alloc(64 * 160 * 2);
    float* bna = (float*)alloc(64 * 4);
    _Float16* nodeWi = (_Float16*)alloc((size_t)N_NODES * 64 * 2);
    _Float16* h = (_Float16*)alloc((size_t)N_EDGES * 64 * 2);
    _Float16* aggA = (_Float16*)alloc((size_t)N_NODES * 64 * 2);
    _Float16* aggB = (_Float16*)alloc((size_t)N_NODES * 64 * 2);
    float* g = (float*)alloc((size_t)N_GRAPHS * 64 * 4);

    hipLaunchKernelGGL(k_fold, dim3(1), dim3(64), 0, stream, We, be, Wi, bi, Wn, bn, Wa, ba,
                       Wl, WeWi, bfold, WlT16, WTn, bnWi, WTo, bna);
    hipLaunchKernelGGL(k_node, dim3(N_NODES / 64), dim3(256), 0, stream, nf, WTn, bnWi, nodeWi);
    hipMemsetAsync(aggA, 0, (size_t)N_NODES * 64 * 2, stream);
    hipLaunchKernelGGL(k_h0, dim3(N_EDGES / 64), dim3(256), 0, stream, ef, src, dst, WeWi,
                       bfold, nodeWi, h, (__half2*)aggA);

    _Float16* cur = aggA;
    _Float16* nxt = aggB;
    for (int l = 0; l < 4; l++) {
        hipMemsetAsync(nxt, 0, (size_t)N_NODES * 64 * 2, stream);
        hipLaunchKernelGGL(k_conv, dim3(N_EDGES / 64), dim3(256), 0, stream, cur, h, nodeWi,
                           ef, src, dst, WeWi, bfold, WlT16, bl, l, (__half2*)nxt);
        _Float16* tmp = cur; cur = nxt; nxt = tmp;
    }
    hipMemsetAsync(g, 0, (size_t)N_GRAPHS * 64 * 4, stream);
    hipLaunchKernelGGL(k_nodeout, dim3(N_NODES / 64), dim3(256), 0, stream, nf, cur, WTo, bna,
                       gid, g);
    hipLaunchKernelGGL(k_head, dim3(N_GRAPHS / 4), dim3(256), 0, stream, g, W1, b1, W2, b2,
                       (float*)d_out);
}